// Round 3
// baseline (375.720 us; speedup 1.0000x reference)
//
#include <hip/hip_runtime.h>
#include <hip/hip_bf16.h>

#define NPTS 500000
#define NGR  64

typedef __bf16 bf16x8 __attribute__((ext_vector_type(8)));
typedef float f32x4 __attribute__((ext_vector_type(4)));
typedef unsigned int u32x4 __attribute__((ext_vector_type(4)));

// ---- workspace layout (bytes), all 16B aligned ----
#define OFF_COMS   0        // f64[256] : per-graph {sx,sy,sz,count} raw sums
#define OFF_COMD   2048     // f64[256] : divided COM
#define OFF_MIND   4096     // u64[64]  : min d2 bits per graph
#define OFF_ARGID  4608     // i32[64]  : min id among d2==min
#define OFF_IDX    4864     // i32[64]
#define OFF_POSD   5120     // f32[256] : pos_dst padded to 4
#define OFF_OUTACC 6144     // u32[8192]: order-preserving max accum
#define OFF_CBIAS  38912    // f32[8192]: per-graph GEMM1 bias row
#define OFF_W1PT   71680    // f32[512] : W1[128:131]^T padded [128][4]
#define OFF_W1AT   73728    // u16[8192]: bf16 W1[64:128]^T [n=128][k=64]
#define OFF_W2T    90112    // u16[16384]: bf16 W2^T [n=128][k=128]
// total 122880 bytes

__device__ __forceinline__ unsigned short f2b(float f) {  // f32 -> bf16 RNE
    union { float f; unsigned u; } v; v.f = f;
    unsigned r = (v.u + 0x7FFFu + ((v.u >> 16) & 1u)) >> 16;
    return (unsigned short)r;
}
// order-preserving float->u32 map (max over u32 == max over float)
__device__ __forceinline__ unsigned mapf(float f) {
    union { float f; unsigned u; } v; v.f = f;
    return ((int)v.u >= 0) ? (v.u | 0x80000000u) : ~v.u;
}
__device__ __forceinline__ bf16x8 pack8(f32x4 a, f32x4 b) {
    union { bf16x8 v; unsigned short s[8]; } u;
    #pragma unroll
    for (int j = 0; j < 4; ++j) { u.s[j] = f2b(a[j]); u.s[4 + j] = f2b(b[j]); }
    return u.v;
}
// deterministic d2 (f64, explicit fma) so both argmin stages get identical bits
__device__ __forceinline__ unsigned long long d2bits(const float* pos, int i,
                                                     const double* comd, int g) {
    double dx = (double)pos[i * 3 + 0] - comd[g * 4 + 0];
    double dy = (double)pos[i * 3 + 1] - comd[g * 4 + 1];
    double dz = (double)pos[i * 3 + 2] - comd[g * 4 + 2];
    double d2 = __builtin_fma(dx, dx, __builtin_fma(dy, dy, dz * dz));
    union { double d; unsigned long long u; } v; v.d = d2;
    return v.u;   // d2 >= 0 -> bits monotone in d2
}

__global__ void k_init(double* coms, unsigned long long* mind, int* argid, unsigned* outacc) {
    int i = blockIdx.x * 256 + threadIdx.x;
    if (i < 8192) outacc[i] = 0u;
    if (i < 256) coms[i] = 0.0;
    if (i < 64) { mind[i] = ~0ULL; argid[i] = 0x7FFFFFFF; }
}

__global__ void k_repack(const float* __restrict__ W1,
                         const float* __restrict__ W2,
                         unsigned short* __restrict__ W1aT,
                         unsigned short* __restrict__ W2T,
                         float* __restrict__ W1pT) {
    int i = blockIdx.x * 256 + threadIdx.x;
    if (i < 8192) {                       // W1aT[n*64+k] = bf16(W1[(64+k)*128+n])
        int n = i >> 6, k = i & 63;
        W1aT[i] = f2b(W1[(64 + k) * 128 + n]);
    } else if (i < 8192 + 16384) {        // W2T[n*128+k] = bf16(W2[k*128+n])
        int j = i - 8192; int n = j >> 7, k = j & 127;
        W2T[j] = f2b(W2[k * 128 + n]);
    } else if (i < 8192 + 16384 + 512) {  // W1pT[n][q], q<3 real, q=3 pad
        int j = i - 24576; int n = j >> 2, q = j & 3;
        W1pT[j] = (q < 3) ? W1[(128 + q) * 128 + n] : 0.f;
    }
}

__global__ void k_com(const float* __restrict__ pos,
                      const int* __restrict__ batch, double* coms) {
    __shared__ double ls[256];
    ls[threadIdx.x] = 0.0;
    __syncthreads();
    int i = blockIdx.x * 256 + threadIdx.x;
    if (i < NPTS) {
        int g = batch[i];
        atomicAdd(&ls[g * 4 + 0], (double)pos[i * 3 + 0]);
        atomicAdd(&ls[g * 4 + 1], (double)pos[i * 3 + 1]);
        atomicAdd(&ls[g * 4 + 2], (double)pos[i * 3 + 2]);
        atomicAdd(&ls[g * 4 + 3], 1.0);
    }
    __syncthreads();
    double v = ls[threadIdx.x];
    if (v != 0.0) atomicAdd(&coms[threadIdx.x], v);
}

__global__ void k_comdiv(const double* __restrict__ coms, double* __restrict__ comd) {
    int t = threadIdx.x;            // 256
    int g = t >> 2;
    double cnt = coms[g * 4 + 3];
    double d = cnt > 1.0 ? cnt : 1.0;
    comd[t] = coms[t] / d;
}

__global__ void k_min1(const float* __restrict__ pos,
                       const int* __restrict__ batch,
                       const double* __restrict__ comd,
                       unsigned long long* mind) {
    __shared__ double lc[256];
    __shared__ unsigned long long lm[64];
    int t = threadIdx.x;
    if (t < 64) lm[t] = ~0ULL;
    lc[t] = comd[t];
    __syncthreads();
    int i = blockIdx.x * 256 + t;
    if (i < NPTS) {
        int g = batch[i];
        atomicMin(&lm[g], d2bits(pos, i, lc, g));
    }
    __syncthreads();
    if (t < 64 && lm[t] != ~0ULL) atomicMin(&mind[t], lm[t]);
}

__global__ void k_min2(const float* __restrict__ pos,
                       const int* __restrict__ batch,
                       const double* __restrict__ comd,
                       const unsigned long long* __restrict__ mind,
                       int* argid) {
    __shared__ double lc[256];
    __shared__ unsigned long long lmin[64];
    __shared__ int li[64];
    int t = threadIdx.x;
    if (t < 64) { lmin[t] = mind[t]; li[t] = 0x7FFFFFFF; }
    lc[t] = comd[t];
    __syncthreads();
    int i = blockIdx.x * 256 + t;
    if (i < NPTS) {
        int g = batch[i];
        if (d2bits(pos, i, lc, g) == lmin[g]) atomicMin(&li[g], i);
    }
    __syncthreads();
    if (t < 64 && li[t] != 0x7FFFFFFF) atomicMin(&argid[t], li[t]);
}

__global__ void k_finalize(const int* __restrict__ argid,
                           const int* __restrict__ batch,
                           const float* __restrict__ pos,
                           const float* __restrict__ lfr,
                           int* idx, float* posd, float* outf) {
    __shared__ int sidx[64];
    int t = threadIdx.x;
    if (t < 64) {
        int id = argid[t];
        if (id < 0 || id > NPTS - 1) id = NPTS - 1;
        sidx[t] = id;
        idx[t] = id;
        outf[8192 + 192 + t] = (float)batch[id];          // batch[idx]
    }
    __syncthreads();
    for (int k = t; k < 192; k += 256) {                  // pos_dst
        int b = k / 3, j = k % 3;
        int id = sidx[b];
        outf[8192 + k] = pos[id * 3 + j];
        posd[b * 4 + j] = pos[id * 3 + j];
    }
    for (int k = t; k < 576; k += 256) {                  // lframes_dst
        int b = k / 9, j = k % 9;
        outf[8192 + 192 + 64 + k] = lfr[sidx[b] * 9 + j];
    }
}

// c[b][c] = sum_k xd[k]*(W1[k][c]-W1[64+k][c]) - sum_j posd[j]*W1[128+j][c] + b1[c]
__global__ void k_cbias(const float* __restrict__ x,
                        const float* __restrict__ W1,
                        const float* __restrict__ b1,
                        const int* __restrict__ idx,
                        const float* __restrict__ posd,
                        float* __restrict__ cbias) {
    int b = blockIdx.x, c = threadIdx.x;
    int id = idx[b];
    float s = b1[c];
    for (int k = 0; k < 64; ++k) {
        float xd = x[id * 64 + k];
        s += xd * (W1[k * 128 + c] - W1[(64 + k) * 128 + c]);
    }
    for (int j = 0; j < 3; ++j) s -= posd[b * 4 + j] * W1[(128 + j) * 128 + c];
    cbias[b * 128 + c] = s;
}

__global__ __launch_bounds__(256) void k_main(
    const float* __restrict__ x,
    const float* __restrict__ pos,
    const int* __restrict__ batch,
    const unsigned short* __restrict__ W1aT,
    const unsigned short* __restrict__ W2T,
    const float* __restrict__ W1pT,
    const float* __restrict__ cbias,
    unsigned* __restrict__ outacc)
{
    __shared__ alignas(16) unsigned short hs[128 * 136];  // +8 pad

    const int tid = threadIdx.x;
    const int w = tid >> 6;
    const int lane = tid & 63;
    const int quad = lane >> 4;
    const int mr = lane & 15;
    const int row0 = blockIdx.x * 128;
    const int rs = row0 + 32 * w;

    // ---------- GEMM1: acc = bf16(x_tile) @ W1a  (M=32/wave, N=128, K=64) ----------
    f32x4 acc[2][8];
    #pragma unroll
    for (int u = 0; u < 2; ++u)
        #pragma unroll
        for (int t = 0; t < 8; ++t) acc[u][t] = (f32x4){0.f, 0.f, 0.f, 0.f};

    bf16x8 afr[2][2];
    #pragma unroll
    for (int u = 0; u < 2; ++u) {
        int gr = rs + 16 * u + mr; if (gr > NPTS - 1) gr = NPTS - 1;
        const f32x4* px = (const f32x4*)(x + gr * 64 + quad * 8);  // cols quad*8..+7
        f32x4 a0 = px[0], a1 = px[1];
        f32x4 a2 = px[8], a3 = px[9];                              // cols +32
        afr[u][0] = pack8(a0, a1);
        afr[u][1] = pack8(a2, a3);
    }
    #pragma unroll
    for (int t = 0; t < 8; ++t) {
        const u32x4* pb = (const u32x4*)(W1aT + (t * 16 + mr) * 64 + quad * 8);
        bf16x8 bv0 = __builtin_bit_cast(bf16x8, pb[0]);
        bf16x8 bv1 = __builtin_bit_cast(bf16x8, pb[4]);
        #pragma unroll
        for (int u = 0; u < 2; ++u) {
            acc[u][t] = __builtin_amdgcn_mfma_f32_16x16x32_bf16(afr[u][0], bv0, acc[u][t], 0, 0, 0);
            acc[u][t] = __builtin_amdgcn_mfma_f32_16x16x32_bf16(afr[u][1], bv1, acc[u][t], 0, 0, 0);
        }
    }

    // ---------- epilogue1: h = relu(acc + c[g] + pos·W1p) -> LDS bf16 ----------
    #pragma unroll
    for (int u = 0; u < 2; ++u) {
        #pragma unroll
        for (int r = 0; r < 4; ++r) {
            int lrow = 32 * w + 16 * u + quad * 4 + r;   // C/D: row = quad*4+reg
            int gr = row0 + lrow;
            int grc = gr > NPTS - 1 ? NPTS - 1 : gr;
            int g = batch[grc];
            float p0 = pos[grc * 3 + 0];
            float p1 = pos[grc * 3 + 1];
            float p2 = pos[grc * 3 + 2];
            const float* crow = cbias + g * 128;
            #pragma unroll
            for (int t = 0; t < 8; ++t) {
                int col = t * 16 + mr;                   // C/D: col = lane&15
                f32x4 wp = *(const f32x4*)(W1pT + col * 4);
                float v = acc[u][t][r] + crow[col] + p0 * wp[0] + p1 * wp[1] + p2 * wp[2];
                v = fmaxf(v, 0.f);
                hs[lrow * 136 + col] = f2b(v);
            }
        }
    }
    __syncthreads();

    // ---------- GEMM2: acc2 = h_tile @ W2  (M=32/wave, N=128, K=128) ----------
    f32x4 acc2[2][8];
    #pragma unroll
    for (int u = 0; u < 2; ++u)
        #pragma unroll
        for (int t = 0; t < 8; ++t) acc2[u][t] = (f32x4){0.f, 0.f, 0.f, 0.f};

    #pragma unroll
    for (int kk = 0; kk < 4; ++kk) {
        bf16x8 a2[2];
        #pragma unroll
        for (int u = 0; u < 2; ++u) {
            const u32x4* ph = (const u32x4*)(hs + (32 * w + 16 * u + mr) * 136 + kk * 32 + quad * 8);
            a2[u] = __builtin_bit_cast(bf16x8, ph[0]);
        }
        #pragma unroll
        for (int t = 0; t < 8; ++t) {
            const u32x4* pb = (const u32x4*)(W2T + (t * 16 + mr) * 128 + kk * 32 + quad * 8);
            bf16x8 bv = __builtin_bit_cast(bf16x8, pb[0]);
            #pragma unroll
            for (int u = 0; u < 2; ++u)
                acc2[u][t] = __builtin_amdgcn_mfma_f32_16x16x32_bf16(a2[u], bv, acc2[u][t], 0, 0, 0);
        }
    }

    // ---------- epilogue2: per-graph column max, atomic into outacc ----------
    int rowg[2][4]; bool rowv[2][4];
    #pragma unroll
    for (int u = 0; u < 2; ++u)
        #pragma unroll
        for (int r = 0; r < 4; ++r) {
            int gr = row0 + 32 * w + 16 * u + quad * 4 + r;
            rowv[u][r] = (gr < NPTS);
            rowg[u][r] = batch[gr < NPTS ? gr : NPTS - 1];
        }
    int gfirst = batch[row0];
    int rlast = row0 + 127; if (rlast > NPTS - 1) rlast = NPTS - 1;
    int glast = batch[rlast];

    for (int g = gfirst; g <= glast; ++g) {
        #pragma unroll
        for (int t = 0; t < 8; ++t) {
            float m = -INFINITY;
            #pragma unroll
            for (int u = 0; u < 2; ++u)
                #pragma unroll
                for (int r = 0; r < 4; ++r)
                    if (rowv[u][r] && rowg[u][r] == g) m = fmaxf(m, acc2[u][t][r]);
            m = fmaxf(m, __shfl_xor(m, 16));
            m = fmaxf(m, __shfl_xor(m, 32));
            unsigned mb = __builtin_bit_cast(unsigned, m);
            if (quad == 0 && mb != 0xFF800000u)          // valid (not -inf)
                atomicMax(&outacc[g * 128 + t * 16 + mr], mapf(m));
        }
    }
}

__global__ void k_out(const unsigned* __restrict__ outacc,
                      const float* __restrict__ b2v,
                      float* __restrict__ outf) {
    int i = blockIdx.x * 256 + threadIdx.x;   // 8192 threads
    unsigned key = outacc[i];
    float v;
    if (key == 0u) {
        v = -300.f;                            // diagnostic: cell never updated
    } else {
        unsigned bits = (key & 0x80000000u) ? (key & 0x7FFFFFFFu) : ~key;
        union { unsigned u; float f; } c; c.u = bits; v = c.f;
    }
    outf[i] = v + b2v[i & 127];
}

extern "C" void kernel_launch(void* const* d_in, const int* in_sizes, int n_in,
                              void* d_out, int out_size, void* d_ws, size_t ws_size,
                              hipStream_t stream) {
    const float* x   = (const float*)d_in[0];
    const float* pos = (const float*)d_in[1];
    const int*   bat = (const int*)d_in[2];
    const float* lfr = (const float*)d_in[3];
    const float* W1  = (const float*)d_in[4];
    const float* b1  = (const float*)d_in[5];
    const float* W2  = (const float*)d_in[6];
    const float* b2v = (const float*)d_in[7];
    float* outf = (float*)d_out;

    char* ws = (char*)d_ws;
    double*             coms   = (double*)(ws + OFF_COMS);
    double*             comd   = (double*)(ws + OFF_COMD);
    unsigned long long* mind   = (unsigned long long*)(ws + OFF_MIND);
    int*                argid  = (int*)(ws + OFF_ARGID);
    int*                idx    = (int*)(ws + OFF_IDX);
    float*              posd   = (float*)(ws + OFF_POSD);
    unsigned*           outacc = (unsigned*)(ws + OFF_OUTACC);
    float*              cbias  = (float*)(ws + OFF_CBIAS);
    float*              W1pT   = (float*)(ws + OFF_W1PT);
    unsigned short*     W1aT   = (unsigned short*)(ws + OFF_W1AT);
    unsigned short*     W2T    = (unsigned short*)(ws + OFF_W2T);

    const int nblk = (NPTS + 255) / 256;      // 1954
    const int tblk = (NPTS + 127) / 128;      // 3907

    k_init<<<32, 256, 0, stream>>>(coms, mind, argid, outacc);
    k_repack<<<98, 256, 0, stream>>>(W1, W2, W1aT, W2T, W1pT);
    k_com<<<nblk, 256, 0, stream>>>(pos, bat, coms);
    k_comdiv<<<1, 256, 0, stream>>>(coms, comd);
    k_min1<<<nblk, 256, 0, stream>>>(pos, bat, comd, mind);
    k_min2<<<nblk, 256, 0, stream>>>(pos, bat, comd, mind, argid);
    k_finalize<<<1, 256, 0, stream>>>(argid, bat, pos, lfr, idx, posd, outf);
    k_cbias<<<64, 128, 0, stream>>>(x, W1, b1, idx, posd, cbias);
    k_main<<<tblk, 256, 0, stream>>>(x, pos, bat, W1aT, W2T, W1pT, cbias, outacc);
    k_out<<<32, 256, 0, stream>>>(outacc, b2v, outf);
}